// Round 7
// baseline (563.970 us; speedup 1.0000x reference)
//
#include <hip/hip_runtime.h>

// ---------------------------------------------------------------------------
// SelfInteraction: 2 layers of (tensor-square -> invariant-gated MLP -> equiv
// linear) + residual + eq-layernorm, N=16384 rows, C=128, all fp32 I/O.
// fp16 hi/lo split-precision MFMA GEMMs (22-bit effective mantissa).
// Revision r7 (vs r6, 357us):
//   * K-loop is now LDS-FREE and BARRIER-FREE: each wave loads its 12
//     fragments (A_hi/A_lo x4 rows, B_hi/B_lo x2 cols) directly from global
//     per 32-k chunk and issues 24 MFMA. In-block reuse was only 2x, already
//     covered by XCD-grouped L2 -- LDS staging bought little and cost the
//     bursty vmcnt(0)+barrier stall that pinned every GEMM at ~13% MfmaUtil
//     / 2760 cyc per 770-cyc chunk (r3/r4/r6 signature).
//   * Occupancy: VGPR ~110, __launch_bounds__(256,4) -> 16 waves/CU (was ~7);
//     epilogue LDS shrunk to 16 KB (no main-loop buffers).
//   * Keeps: fused 3-pass chunks (24 MFMA/wave/chunk), [col][2K] weights,
//     128x64 tiles, XCD-grouped remap, LDS-staged coalesced epilogues.
// ---------------------------------------------------------------------------

typedef _Float16 half8 __attribute__((ext_vector_type(8)));
typedef float floatx4 __attribute__((ext_vector_type(4)));

static inline int cdiv_h(int a, int b){ return (a + b - 1) / b; }

// ---------------------------- device helpers -------------------------------

__device__ __forceinline__ float wave_sum64(float x){
  #pragma unroll
  for (int m = 32; m; m >>= 1) x += __shfl_xor(x, m, 64);
  return x;
}

__device__ __forceinline__ void split_store(_Float16* p0, _Float16* p1, float v){
  _Float16 hi = (_Float16)v;
  *p0 = hi;
  *p1 = (_Float16)(v - (float)hi);
}

// pack (hi,lo) split of v into one uint (hi in low 16 bits)
__device__ __forceinline__ unsigned int pack_split(float v){
  union { _Float16 h[2]; unsigned int u; } pk;
  _Float16 hi = (_Float16)v;
  pk.h[0] = hi;
  pk.h[1] = (_Float16)(v - (float)hi);
  return pk.u;
}

// 4 packed (hi,lo) uints -> (hi0..3, lo0..3) as two uint2
__device__ __forceinline__ void unzip16(uint4 p, uint2& hi, uint2& lo){
  hi.x = (p.x & 0xffffu) | (p.y << 16);
  hi.y = (p.z & 0xffffu) | (p.w << 16);
  lo.x = (p.x >> 16) | (p.y & 0xffff0000u);
  lo.y = (p.z >> 16) | (p.w & 0xffff0000u);
}

// XCD-grouped remap: with round-robin dispatch (block i -> XCD i&7), all nx
// col-panel blocks of row panel y get the same (i&7) -> same XCD L2.
// Bijective for ny%8==0; identity fallback otherwise (correctness-safe).
__device__ __forceinline__ void remap_xcd(int id, int nx, int ny, int& x, int& y){
  if (ny & 7){ x = id % nx; y = id / nx; return; }
  int xcd = id & 7, q = id >> 3, t = q / nx;
  x = q - t*nx; y = xcd + (t << 3);
}

// ---------------------------- weight prep ----------------------------------
// All 8 weight-prep jobs in one launch. w row-major (K, ldw); writes BT'
// [col][2K]: seg0=hi, seg1=lo.
__global__ __launch_bounds__(256) void prep_all(const float* __restrict__ w1,
                                                const float* __restrict__ w2,
                                                const float* __restrict__ w0,
                                                const float* __restrict__ wv,
                                                _Float16* __restrict__ W){
  const int PER_L = 475136;                      // 147456+245760+49152+32768
  int idx = blockIdx.x*256 + threadIdx.x;
  if (idx >= 2*PER_L) return;
  int l = idx / PER_L;
  int r = idx - l*PER_L;
  const float RS384 = 0.051031036307982884f;     // 1/sqrt(384)
  _Float16* WL = W + (size_t)l*950272;
  const float* src; _Float16* dst; int K, ldw, col, k; float scale;
  if (r < 147456){                               // w1: 384x384
    src = w1 + (size_t)l*147456; dst = WL;            K = 384; ldw = 384; scale = RS384;
    col = r / 384; k = r - col*384;
  } else if (r < 393216){                        // w2: 384x768, first 640 cols
    r -= 147456;
    src = w2 + (size_t)l*294912; dst = WL + 294912;   K = 384; ldw = 768; scale = RS384;
    col = r / 384; k = r - col*384;
  } else if (r < 442368){                        // w0: 384x128
    r -= 393216;
    src = w0 + (size_t)l*49152;  dst = WL + 786432;   K = 384; ldw = 128; scale = RS384;
    col = r / 384; k = r - col*384;
  } else {                                       // wv: 256x128
    r -= 442368;
    src = wv + (size_t)l*32768;  dst = WL + 884736;   K = 256; ldw = 128; scale = 0.0625f;
    col = r / 256; k = r - col*256;
  }
  float v = src[(size_t)k*ldw + col] * scale;
  _Float16 hi = (_Float16)v;
  _Float16 lo = (_Float16)(v - (float)hi);
  size_t b = (size_t)col*2*K + k;
  dst[b]     = hi;
  dst[b + K] = lo;
}

// ---------------------------- E0: unpack x + build sc' ---------------------
__global__ __launch_bounds__(256) void e0_fused(const float* __restrict__ x,
                                                float* __restrict__ S,
                                                float* __restrict__ V,
                                                _Float16* __restrict__ A1,
                                                int row0){
  __shared__ alignas(16) float lx[4][512];
  const int n0 = blockIdx.x*4;
  const int tid = threadIdx.x;
  const float4* xs = (const float4*)(x + (size_t)(row0 + n0)*512);
  float4* ls = (float4*)(&lx[0][0]);
  ls[tid]       = xs[tid];
  ls[tid + 256] = xs[tid + 256];
  __syncthreads();
  const int w = tid >> 6, lane = tid & 63;
  const int n = n0 + w;
  const float* row = &lx[w][0];
  #pragma unroll
  for (int h = 0; h < 2; ++h){
    int ch = h*64 + lane;
    float s = row[ch];
    S[(size_t)n*128 + ch] = s;
    float vv = 0.f;
    #pragma unroll
    for (int d = 0; d < 3; ++d){
      float vd = row[128 + ch*3 + d];
      V[((size_t)n*3 + d)*128 + ch] = vd;
      vv += vd*vd;
    }
    float vals[3] = { s, s*s, vv * 0.5773502691896258f };   // 1/sqrt(3)
    #pragma unroll
    for (int q = 0; q < 3; ++q){
      size_t b = (size_t)n*768 + q*128 + ch;
      split_store(&A1[b], &A1[b + 384], vals[q]);
    }
  }
}

// ---------------------------- E3: residual + LN / final --------------------
__global__ __launch_bounds__(256) void e3_fin(float* __restrict__ S, float* __restrict__ V,
                                              const float* __restrict__ OS, const float* __restrict__ OV,
                                              const float* __restrict__ g0, const float* __restrict__ g1,
                                              float* __restrict__ out, _Float16* __restrict__ A1,
                                              int row0, int doln){
  int n = blockIdx.x*4 + (threadIdx.x >> 6);
  int lane = threadIdx.x & 63;
  size_t sb = (size_t)n*128;
  size_t vb = (size_t)n*384;
  float s0 = S[sb + lane]      + OS[sb + lane];
  float s1 = S[sb + 64 + lane] + OS[sb + 64 + lane];
  float v[6];
  #pragma unroll
  for (int k = 0; k < 6; ++k) v[k] = V[vb + k*64 + lane] + OV[vb + k*64 + lane];

  if (doln){
    float mu = wave_sum64(s0 + s1) * (1.0f/128.0f);
    float d0 = s0 - mu, d1 = s1 - mu;
    float var = wave_sum64(d0*d0 + d1*d1) * (1.0f/128.0f);
    float sd = sqrtf(var + 1e-6f);
    float vvsum = 0.f;
    #pragma unroll
    for (int k = 0; k < 6; ++k) vvsum += v[k]*v[k];
    float rms = sqrtf(wave_sum64(vvsum) * (1.0f/384.0f) + 1e-6f);
    float s0n = d0 / sd * g0[lane];
    float s1n = d1 / sd * g0[64 + lane];
    S[sb + lane]      = s0n;
    S[sb + 64 + lane] = s1n;
    float vn[6];
    #pragma unroll
    for (int k = 0; k < 6; ++k){
      int j = k*64 + lane;
      vn[k] = v[k] / rms * g1[j & 127];
      V[vb + j] = vn[k];
    }
    // emit A1 = sc' = [s, s^2, |v|^2/sqrt3] hi/lo for the next layer
    float vv_a = vn[0]*vn[0] + vn[2]*vn[2] + vn[4]*vn[4];   // ch = lane
    float vv_b = vn[1]*vn[1] + vn[3]*vn[3] + vn[5]*vn[5];   // ch = 64+lane
    float va[3] = { s0n, s0n*s0n, vv_a * 0.5773502691896258f };
    float vbv[3]= { s1n, s1n*s1n, vv_b * 0.5773502691896258f };
    #pragma unroll
    for (int q = 0; q < 3; ++q){
      size_t ba = (size_t)n*768 + q*128 + lane;
      split_store(&A1[ba], &A1[ba + 384], va[q]);
      size_t bb = ba + 64;
      split_store(&A1[bb], &A1[bb + 384], vbv[q]);
    }
  } else {
    size_t ob = (size_t)(row0 + n)*512;
    out[ob + lane]      = s0;
    out[ob + 64 + lane] = s1;
    #pragma unroll
    for (int k = 0; k < 6; ++k){
      int j = k*64 + lane;
      int d = j >> 7, ch = j & 127;
      out[ob + 128 + ch*3 + d] = v[k];
    }
  }
}

// ---------------------------- split-GEMM main loop (128x64 tile) -----------
// C[128 x 64] += A[128 x 2*kbase (hi|lo)] x BT[64 x 2*kbase (hi|lo)]^T
// = hi*hi + hi*lo + lo*hi, fused per 32-k chunk: 24 MFMA/wave/chunk.
// NO LDS, NO BARRIERS: each wave loads its 12 fragments (half8) straight
// from global. Per-lane pattern: 16 rows (lane&15) x 64B (lane>>4) sectors;
// the 2x in-block operand duplication is absorbed by L2 (XCD-grouped grid).
// The +kbase lo offset (<=768B) folds into the load's 13-bit imm offset.
__device__ __forceinline__ void gemm_mainloop(const _Float16* __restrict__ A,
                                              const _Float16* __restrict__ BT,
                                              int lda, int kbase, int m0, int c0,
                                              floatx4 (&acc)[4][2]){
  const int nsc = kbase >> 5;
  const int ldbt = 2*kbase;
  const int tid = threadIdx.x;
  const int wave = tid >> 6, lane = tid & 63;
  const int wm = wave & 1, wn = wave >> 1;
  const int r = lane & 15, kg = lane >> 4;

  const _Float16* pa0 = A + (size_t)(m0 + wm*64 +  0 + r)*lda + kg*8;
  const _Float16* pa1 = A + (size_t)(m0 + wm*64 + 16 + r)*lda + kg*8;
  const _Float16* pa2 = A + (size_t)(m0 + wm*64 + 32 + r)*lda + kg*8;
  const _Float16* pa3 = A + (size_t)(m0 + wm*64 + 48 + r)*lda + kg*8;
  const _Float16* pb0 = BT + (size_t)(c0 + wn*32 +  0 + r)*ldbt + kg*8;
  const _Float16* pb1 = BT + (size_t)(c0 + wn*32 + 16 + r)*ldbt + kg*8;

  for (int c = 0; c < nsc; ++c){
    half8 ah[4], al[4], bh[2], bl[2];
    ah[0] = *(const half8*)pa0;  al[0] = *(const half8*)(pa0 + kbase);
    ah[1] = *(const half8*)pa1;  al[1] = *(const half8*)(pa1 + kbase);
    ah[2] = *(const half8*)pa2;  al[2] = *(const half8*)(pa2 + kbase);
    ah[3] = *(const half8*)pa3;  al[3] = *(const half8*)(pa3 + kbase);
    bh[0] = *(const half8*)pb0;  bl[0] = *(const half8*)(pb0 + kbase);
    bh[1] = *(const half8*)pb1;  bl[1] = *(const half8*)(pb1 + kbase);
    pa0 += 32; pa1 += 32; pa2 += 32; pa3 += 32; pb0 += 32; pb1 += 32;
    #pragma unroll
    for (int mt = 0; mt < 4; ++mt)
      #pragma unroll
      for (int nt = 0; nt < 2; ++nt)
        acc[mt][nt] = __builtin_amdgcn_mfma_f32_16x16x32_f16(ah[mt], bh[nt], acc[mt][nt], 0, 0, 0);
    #pragma unroll
    for (int mt = 0; mt < 4; ++mt)
      #pragma unroll
      for (int nt = 0; nt < 2; ++nt)
        acc[mt][nt] = __builtin_amdgcn_mfma_f32_16x16x32_f16(ah[mt], bl[nt], acc[mt][nt], 0, 0, 0);
    #pragma unroll
    for (int mt = 0; mt < 4; ++mt)
      #pragma unroll
      for (int nt = 0; nt < 2; ++nt)
        acc[mt][nt] = __builtin_amdgcn_mfma_f32_16x16x32_f16(al[mt], bh[nt], acc[mt][nt], 0, 0, 0);
  }
}

// MODE 1: silu + hi/lo split into OUT (=A2, lda 768, lo at +384).
// MODE 2: fused gating epilogue (G never materialized):
//   c0<384 : A1 <- (A1hi+A1lo)*g in place (patch RMW through LDS)
//   c0>=384: A4[(n*3+d)*512+mm] <- vec[n,mm,d]*g hi/lo
// Epilogue HBM traffic staged through 16 KB LDS (coalesced full-line runs);
// scratch uses XOR swizzle pc = cl ^ (kg<<4) matched by the movers.
template<int MODE>
__global__ __launch_bounds__(256, 4) void gemm_split(const _Float16* __restrict__ A,
                                                     const _Float16* __restrict__ BT,
                                                     _Float16* __restrict__ OUT,
                                                     const float* __restrict__ S,
                                                     const float* __restrict__ V,
                                                     _Float16* __restrict__ A1g,
                                                     _Float16* __restrict__ A4,
                                                     int lda, int kbase, int nx, int ny){
  __shared__ alignas(16) char scr[16384];        // epilogue scratch only
  int bx, by; remap_xcd(blockIdx.x, nx, ny, bx, by);
  const int c0 = bx << 6, m0 = by << 7;
  floatx4 acc[4][2];
  #pragma unroll
  for (int i = 0; i < 4; ++i)
    #pragma unroll
    for (int j = 0; j < 2; ++j) acc[i][j] = (floatx4){0.f, 0.f, 0.f, 0.f};

  gemm_mainloop(A, BT, lda, kbase, m0, c0, acc);

  const int tid = threadIdx.x;
  const int wave = tid >> 6, lane = tid & 63;
  const int wm = wave & 1, wn = wave >> 1;
  const int r = lane & 15, kg = lane >> 4;

  if (MODE == 1){
    #pragma unroll
    for (int h = 0; h < 2; ++h){
      __syncthreads();
      if (wm == h){
        #pragma unroll
        for (int mt = 0; mt < 4; ++mt)
          #pragma unroll
          for (int nt = 0; nt < 2; ++nt)
            #pragma unroll
            for (int i = 0; i < 4; ++i){
              int rl = mt*16 + kg*4 + i;          // 0..63
              int cl = wn*32 + nt*16 + r;         // 0..63
              int pc = cl ^ (kg << 4);
              float g = acc[mt][nt][i];
              float hh = g / (1.0f + __expf(-g)); // silu
              *(unsigned int*)(scr + rl*256 + pc*4) = pack_split(hh);
            }
      }
      __syncthreads();
      #pragma unroll 1
      for (int j = 0; j < 4; ++j){
        int lin = j*256 + tid, rl = lin >> 4, seg = lin & 15;
        int cs = seg ^ (((rl >> 2) & 3) << 2);
        uint4 p = *(const uint4*)(scr + rl*256 + cs*16);
        uint2 hi, lo; unzip16(p, hi, lo);
        _Float16* rowp = OUT + (size_t)(m0 + h*64 + rl)*768 + c0 + seg*4;
        *(uint2*)rowp         = hi;
        *(uint2*)(rowp + 384) = lo;
      }
    }
  } else if (c0 < 384){
    // ---- sc-gate: RMW the A1 hi/lo 64-col patch through LDS
    #pragma unroll
    for (int h = 0; h < 2; ++h){
      __syncthreads();
      #pragma unroll 1
      for (int j = 0; j < 2; ++j){
        int lin = j*256 + tid, rl = lin >> 3, seg = lin & 7;
        int cs = seg ^ (((rl >> 2) & 3) << 1);
        const _Float16* gp = A1g + (size_t)(m0 + h*64 + rl)*768 + c0 + seg*8;
        *(float4*)(scr + rl*128 + cs*16)        = *(const float4*)gp;         // hi
        *(float4*)(scr + 8192 + rl*128 + cs*16) = *(const float4*)(gp + 384); // lo
      }
      __syncthreads();
      if (wm == h){
        #pragma unroll
        for (int mt = 0; mt < 4; ++mt)
          #pragma unroll
          for (int nt = 0; nt < 2; ++nt)
            #pragma unroll
            for (int i = 0; i < 4; ++i){
              int rl = mt*16 + kg*4 + i;
              int cl = wn*32 + nt*16 + r;
              int pc = cl ^ (kg << 4);
              _Float16* phi = (_Float16*)scr + rl*64 + pc;
              _Float16* plo = (_Float16*)(scr + 8192) + rl*64 + pc;
              float sc = (float)*phi + (float)*plo;
              split_store(phi, plo, sc * acc[mt][nt][i]);
            }
      }
      __syncthreads();
      #pragma unroll 1
      for (int j = 0; j < 2; ++j){
        int lin = j*256 + tid, rl = lin >> 3, seg = lin & 7;
        int cs = seg ^ (((rl >> 2) & 3) << 1);
        _Float16* gp = A1g + (size_t)(m0 + h*64 + rl)*768 + c0 + seg*8;
        *(float4*)gp         = *(const float4*)(scr + rl*128 + cs*16);
        *(float4*)(gp + 384) = *(const float4*)(scr + 8192 + rl*128 + cs*16);
      }
    }
  } else {
    // ---- vec-gate: c0 in {384,448,512,576}; mm panel = c0-384
    const int mm0 = c0 - 384;
    const int ch0 = mm0 & 127;
    if (mm0 >= 128){
      // fold sqrt2*S into acc once
      #pragma unroll
      for (int mt = 0; mt < 4; ++mt)
        #pragma unroll
        for (int nt = 0; nt < 2; ++nt)
          #pragma unroll
          for (int i = 0; i < 4; ++i){
            int row = m0 + wm*64 + mt*16 + kg*4 + i;
            int cl  = wn*32 + nt*16 + r;
            acc[mt][nt][i] *= 1.4142135623730951f * S[(size_t)row*128 + ch0 + cl];
          }
    }
    for (int d = 0; d < 3; ++d){
      #pragma unroll
      for (int h = 0; h < 2; ++h){
        __syncthreads();
        #pragma unroll 1
        for (int j = 0; j < 4; ++j){             // V patch: 64 rows x 256 B
          int lin = j*256 + tid, rl = lin >> 4, seg = lin & 15;
          int cs = seg ^ (((rl >> 2) & 3) << 2);
          *(float4*)(scr + rl*256 + cs*16) =
            *(const float4*)(V + ((size_t)(m0 + h*64 + rl)*3 + d)*128 + ch0 + seg*4);
        }
        __syncthreads();
        if (wm == h){
          #pragma unroll
          for (int mt = 0; mt < 4; ++mt)
            #pragma unroll
            for (int nt = 0; nt < 2; ++nt)
              #pragma unroll
              for (int i = 0; i < 4; ++i){
                int rl = mt*16 + kg*4 + i;
                int cl = wn*32 + nt*16 + r;
                int pc = cl ^ (kg << 4);
                float* pw = (float*)(scr + rl*256) + pc;
                *(unsigned int*)pw = pack_split(*pw * acc[mt][nt][i]);
              }
        }
        __syncthreads();
        #pragma unroll 1
        for (int j = 0; j < 4; ++j){
          int lin = j*256 + tid, rl = lin >> 4, seg = lin & 15;
          int cs = seg ^ (((rl >> 2) & 3) << 2);
          uint4 p = *(const uint4*)(scr + rl*256 + cs*16);
          uint2 hi, lo; unzip16(p, hi, lo);
          _Float16* rowp = A4 + ((size_t)(m0 + h*64 + rl)*3 + d)*512 + mm0 + seg*4;
          *(uint2*)rowp         = hi;
          *(uint2*)(rowp + 256) = lo;
        }
      }
    }
  }
}

// GEMM0 (A1 x W0 -> OS, 2*ny0 blocks) and GEMMV (A4 x WV -> OV, 2*ny1 blocks)
// in one dispatch; each part XCD-remapped; plain f32 coalesced store; no LDS.
__global__ __launch_bounds__(256, 4) void gemm_pair(const _Float16* __restrict__ Aa,
                                                    const _Float16* __restrict__ Ba,
                                                    float* __restrict__ Ca, int ny0,
                                                    const _Float16* __restrict__ Ab,
                                                    const _Float16* __restrict__ Bb,
                                                    float* __restrict__ Cb, int ny1){
  const _Float16 *A, *BT; float* C; int lda, kbase, bx, by;
  const int id = blockIdx.x;
  if (id < 2*ny0){
    remap_xcd(id, 2, ny0, bx, by);
    A = Aa; BT = Ba; C = Ca; lda = 768; kbase = 384;
  } else {
    remap_xcd(id - 2*ny0, 2, ny1, bx, by);
    A = Ab; BT = Bb; C = Cb; lda = 512; kbase = 256;
  }
  const int c0 = bx << 6, m0 = by << 7;
  floatx4 acc[4][2];
  #pragma unroll
  for (int i = 0; i < 4; ++i)
    #pragma unroll
    for (int j = 0; j < 2; ++j) acc[i][j] = (floatx4){0.f, 0.f, 0.f, 0.f};

  gemm_mainloop(A, BT, lda, kbase, m0, c0, acc);

  const int wave = threadIdx.x >> 6, lane = threadIdx.x & 63;
  const int wm = wave & 1, wn = wave >> 1;
  const int r = lane & 15, kg = lane >> 4;
  #pragma unroll
  for (int mt = 0; mt < 4; ++mt)
    #pragma unroll
    for (int nt = 0; nt < 2; ++nt)
      #pragma unroll
      for (int i = 0; i < 4; ++i){
        const int row = m0 + wm*64 + mt*16 + kg*4 + i;
        const int col = c0 + wn*32 + nt*16 + r;
        C[(size_t)row*128 + col] = acc[mt][nt][i];
      }
}

// ---------------------------- host launcher --------------------------------

extern "C" void kernel_launch(void* const* d_in, const int* in_sizes, int n_in,
                              void* d_out, int out_size, void* d_ws, size_t ws_size,
                              hipStream_t stream){
  const float* x  = (const float*)d_in[0];
  const float* w1 = (const float*)d_in[1];
  const float* w2 = (const float*)d_in[2];
  const float* w0 = (const float*)d_in[3];
  const float* wv = (const float*)d_in[4];
  const float* g0 = (const float*)d_in[5];
  const float* g1 = (const float*)d_in[6];
  float* out = (float*)d_out;
  const int N = in_sizes[0] / 512;                 // 16384

  // split-weight arena: per layer 950,272 halves ([col][2K] hi|lo)
  const size_t HL = 950272;
  _Float16* W = (_Float16*)d_ws;
  const size_t wbytes = 2*HL*2;                    // 3,801,088 B

  // pick N-chunking that fits ws (activations cost 10240 B/row)
  int cnum = 128;
  for (int cc = 1; cc <= 128; cc <<= 1){
    size_t need = wbytes + (size_t)(N/cc)*10240;
    if (need <= ws_size){ cnum = cc; break; }
  }
  const int R = N / cnum;                          // multiple of 128
  const int ny = R / 128;

  char* p = (char*)d_ws + wbytes;
  float*    Sst = (float*)p;     p += (size_t)R*512;
  float*    Vst = (float*)p;     p += (size_t)R*1536;
  _Float16* A1  = (_Float16*)p;  p += (size_t)R*1536;   // sc' then gated sc'
  _Float16* A2  = (_Float16*)p;  p += (size_t)R*1536;   // h'
  _Float16* A4  = (_Float16*)p;  p += (size_t)R*3072;   // gated vec' (3R x 512)
  float*    OS  = (float*)p;     p += (size_t)R*512;
  float*    OV  = (float*)p;     p += (size_t)R*1536;

  // weight prep (runs every call; ws is re-poisoned before each timed launch)
  prep_all<<<cdiv_h(2*475136,256),256,0,stream>>>(w1, w2, w0, wv, W);

  for (int chk = 0; chk < cnum; ++chk){
    const int row0 = chk*R;
    e0_fused<<<R/4,256,0,stream>>>(x, Sst, Vst, A1, row0);
    for (int l = 0; l < 2; ++l){
      _Float16* W1p = W + (size_t)l*HL;
      _Float16* W2p = W1p + 294912;
      _Float16* W0p = W1p + 786432;
      _Float16* WVp = W1p + 884736;
      gemm_split<1><<<6*ny,256,0,stream>>>(A1, W1p, A2,
          nullptr, nullptr, nullptr, nullptr, 768, 384, 6, ny);
      gemm_split<2><<<10*ny,256,0,stream>>>(A2, W2p, nullptr,
          Sst, Vst, A1, A4, 768, 384, 10, ny);
      gemm_pair<<<8*ny,256,0,stream>>>(A1, W0p, OS, ny, A4, WVp, OV, 3*ny);
      e3_fin<<<R/4,256,0,stream>>>(Sst, Vst, OS, OV, g0, g1, out, A1, row0, (l == 0) ? 1 : 0);
    }
  }
}

// Round 8
// 340.173 us; speedup vs baseline: 1.6579x; 1.6579x over previous
//
#include <hip/hip_runtime.h>

// ---------------------------------------------------------------------------
// SelfInteraction: 2 layers of (tensor-square -> invariant-gated MLP -> equiv
// linear) + residual + eq-layernorm, N=16384 rows, C=128, all fp32 I/O.
// fp16 hi/lo split-precision MFMA GEMMs (22-bit effective mantissa).
// Revision r8 (vs r6 @357us; r7's LDS-free loop reverted -- it was L1/TA
// line-throughput-bound: 16-line scattered loads x12/wave -> 8.7% MfmaUtil):
//   * K-loop identical to r6 (fused 3-pass chunks, 24 MFMA/wave/barrier,
//     global_load_lds staging, 2x24KB buffers, plain __syncthreads).
//   * Epilogue h-phases MERGED: full 128-row patches in the 48 KB LDS.
//     - ALL 4 waves participate in every modify step (was: half idle).
//     - Barriers per block: MODE1 4->2, sc-gate 6->3, vec-gate 18->9.
//   * Keeps: [col][2K] weights, 128x64 tiles, XCD-grouped remap, both-sides
//     swizzles, LDS-staged coalesced epilogue I/O.
// ---------------------------------------------------------------------------

typedef _Float16 half8 __attribute__((ext_vector_type(8)));
typedef float floatx4 __attribute__((ext_vector_type(4)));

static inline int cdiv_h(int a, int b){ return (a + b - 1) / b; }

// ---------------------------- device helpers -------------------------------

__device__ __forceinline__ void stage16(const char* gaddr, char* lds_base){
  // dest = wave-uniform base + lane*16 (measured semantics, learn_hip m104/m108)
  __builtin_amdgcn_global_load_lds((const __attribute__((address_space(1))) unsigned int*)gaddr,
                                   (__attribute__((address_space(3))) unsigned int*)lds_base,
                                   16, 0, 0);
}

__device__ __forceinline__ float wave_sum64(float x){
  #pragma unroll
  for (int m = 32; m; m >>= 1) x += __shfl_xor(x, m, 64);
  return x;
}

__device__ __forceinline__ void split_store(_Float16* p0, _Float16* p1, float v){
  _Float16 hi = (_Float16)v;
  *p0 = hi;
  *p1 = (_Float16)(v - (float)hi);
}

// pack (hi,lo) split of v into one uint (hi in low 16 bits)
__device__ __forceinline__ unsigned int pack_split(float v){
  union { _Float16 h[2]; unsigned int u; } pk;
  _Float16 hi = (_Float16)v;
  pk.h[0] = hi;
  pk.h[1] = (_Float16)(v - (float)hi);
  return pk.u;
}

// 4 packed (hi,lo) uints -> (hi0..3, lo0..3) as two uint2
__device__ __forceinline__ void unzip16(uint4 p, uint2& hi, uint2& lo){
  hi.x = (p.x & 0xffffu) | (p.y << 16);
  hi.y = (p.z & 0xffffu) | (p.w << 16);
  lo.x = (p.x >> 16) | (p.y & 0xffff0000u);
  lo.y = (p.z >> 16) | (p.w & 0xffff0000u);
}

// XCD-grouped remap: with round-robin dispatch (block i -> XCD i&7), all nx
// col-panel blocks of row panel y get the same (i&7) -> same XCD L2.
// Bijective for ny%8==0; identity fallback otherwise (correctness-safe).
__device__ __forceinline__ void remap_xcd(int id, int nx, int ny, int& x, int& y){
  if (ny & 7){ x = id % nx; y = id / nx; return; }
  int xcd = id & 7, q = id >> 3, t = q / nx;
  x = q - t*nx; y = xcd + (t << 3);
}

// ---------------------------- weight prep ----------------------------------
// All 8 weight-prep jobs in one launch. w row-major (K, ldw); writes BT'
// [col][2K]: seg0=hi, seg1=lo.
__global__ __launch_bounds__(256) void prep_all(const float* __restrict__ w1,
                                                const float* __restrict__ w2,
                                                const float* __restrict__ w0,
                                                const float* __restrict__ wv,
                                                _Float16* __restrict__ W){
  const int PER_L = 475136;                      // 147456+245760+49152+32768
  int idx = blockIdx.x*256 + threadIdx.x;
  if (idx >= 2*PER_L) return;
  int l = idx / PER_L;
  int r = idx - l*PER_L;
  const float RS384 = 0.051031036307982884f;     // 1/sqrt(384)
  _Float16* WL = W + (size_t)l*950272;
  const float* src; _Float16* dst; int K, ldw, col, k; float scale;
  if (r < 147456){                               // w1: 384x384
    src = w1 + (size_t)l*147456; dst = WL;            K = 384; ldw = 384; scale = RS384;
    col = r / 384; k = r - col*384;
  } else if (r < 393216){                        // w2: 384x768, first 640 cols
    r -= 147456;
    src = w2 + (size_t)l*294912; dst = WL + 294912;   K = 384; ldw = 768; scale = RS384;
    col = r / 384; k = r - col*384;
  } else if (r < 442368){                        // w0: 384x128
    r -= 393216;
    src = w0 + (size_t)l*49152;  dst = WL + 786432;   K = 384; ldw = 128; scale = RS384;
    col = r / 384; k = r - col*384;
  } else {                                       // wv: 256x128
    r -= 442368;
    src = wv + (size_t)l*32768;  dst = WL + 884736;   K = 256; ldw = 128; scale = 0.0625f;
    col = r / 256; k = r - col*256;
  }
  float v = src[(size_t)k*ldw + col] * scale;
  _Float16 hi = (_Float16)v;
  _Float16 lo = (_Float16)(v - (float)hi);
  size_t b = (size_t)col*2*K + k;
  dst[b]     = hi;
  dst[b + K] = lo;
}

// ---------------------------- E0: unpack x + build sc' ---------------------
__global__ __launch_bounds__(256) void e0_fused(const float* __restrict__ x,
                                                float* __restrict__ S,
                                                float* __restrict__ V,
                                                _Float16* __restrict__ A1,
                                                int row0){
  __shared__ alignas(16) float lx[4][512];
  const int n0 = blockIdx.x*4;
  const int tid = threadIdx.x;
  const float4* xs = (const float4*)(x + (size_t)(row0 + n0)*512);
  float4* ls = (float4*)(&lx[0][0]);
  ls[tid]       = xs[tid];
  ls[tid + 256] = xs[tid + 256];
  __syncthreads();
  const int w = tid >> 6, lane = tid & 63;
  const int n = n0 + w;
  const float* row = &lx[w][0];
  #pragma unroll
  for (int h = 0; h < 2; ++h){
    int ch = h*64 + lane;
    float s = row[ch];
    S[(size_t)n*128 + ch] = s;
    float vv = 0.f;
    #pragma unroll
    for (int d = 0; d < 3; ++d){
      float vd = row[128 + ch*3 + d];
      V[((size_t)n*3 + d)*128 + ch] = vd;
      vv += vd*vd;
    }
    float vals[3] = { s, s*s, vv * 0.5773502691896258f };   // 1/sqrt(3)
    #pragma unroll
    for (int q = 0; q < 3; ++q){
      size_t b = (size_t)n*768 + q*128 + ch;
      split_store(&A1[b], &A1[b + 384], vals[q]);
    }
  }
}

// ---------------------------- E3: residual + LN / final --------------------
__global__ __launch_bounds__(256) void e3_fin(float* __restrict__ S, float* __restrict__ V,
                                              const float* __restrict__ OS, const float* __restrict__ OV,
                                              const float* __restrict__ g0, const float* __restrict__ g1,
                                              float* __restrict__ out, _Float16* __restrict__ A1,
                                              int row0, int doln){
  int n = blockIdx.x*4 + (threadIdx.x >> 6);
  int lane = threadIdx.x & 63;
  size_t sb = (size_t)n*128;
  size_t vb = (size_t)n*384;
  float s0 = S[sb + lane]      + OS[sb + lane];
  float s1 = S[sb + 64 + lane] + OS[sb + 64 + lane];
  float v[6];
  #pragma unroll
  for (int k = 0; k < 6; ++k) v[k] = V[vb + k*64 + lane] + OV[vb + k*64 + lane];

  if (doln){
    float mu = wave_sum64(s0 + s1) * (1.0f/128.0f);
    float d0 = s0 - mu, d1 = s1 - mu;
    float var = wave_sum64(d0*d0 + d1*d1) * (1.0f/128.0f);
    float sd = sqrtf(var + 1e-6f);
    float vvsum = 0.f;
    #pragma unroll
    for (int k = 0; k < 6; ++k) vvsum += v[k]*v[k];
    float rms = sqrtf(wave_sum64(vvsum) * (1.0f/384.0f) + 1e-6f);
    float s0n = d0 / sd * g0[lane];
    float s1n = d1 / sd * g0[64 + lane];
    S[sb + lane]      = s0n;
    S[sb + 64 + lane] = s1n;
    float vn[6];
    #pragma unroll
    for (int k = 0; k < 6; ++k){
      int j = k*64 + lane;
      vn[k] = v[k] / rms * g1[j & 127];
      V[vb + j] = vn[k];
    }
    // emit A1 = sc' = [s, s^2, |v|^2/sqrt3] hi/lo for the next layer
    float vv_a = vn[0]*vn[0] + vn[2]*vn[2] + vn[4]*vn[4];   // ch = lane
    float vv_b = vn[1]*vn[1] + vn[3]*vn[3] + vn[5]*vn[5];   // ch = 64+lane
    float va[3] = { s0n, s0n*s0n, vv_a * 0.5773502691896258f };
    float vbv[3]= { s1n, s1n*s1n, vv_b * 0.5773502691896258f };
    #pragma unroll
    for (int q = 0; q < 3; ++q){
      size_t ba = (size_t)n*768 + q*128 + lane;
      split_store(&A1[ba], &A1[ba + 384], va[q]);
      size_t bb = ba + 64;
      split_store(&A1[bb], &A1[bb + 384], vbv[q]);
    }
  } else {
    size_t ob = (size_t)(row0 + n)*512;
    out[ob + lane]      = s0;
    out[ob + 64 + lane] = s1;
    #pragma unroll
    for (int k = 0; k < 6; ++k){
      int j = k*64 + lane;
      int d = j >> 7, ch = j & 127;
      out[ob + 128 + ch*3 + d] = v[k];
    }
  }
}

// ---------------------------- split-GEMM main loop (128x64 tile) -----------
// C[128 x 64] += A[128 x 2*kbase (hi|lo)] x BT[64 x 2*kbase (hi|lo)]^T
// computed as hi*hi + hi*lo + lo*hi, all three passes per 32-k-col chunk in
// ONE barrier round: stage {A_hi 8K, A_lo 8K, B_hi 4K, B_lo 4K} = 24 KB/buf,
// 12 ds_read_b128 + 24 MFMA per wave per barrier, nsc (12 or 8) rounds.
// 4 waves: wm=wave&1 row half, wn=wave>>1 col half, acc[4][2] of 16x16.
// LDS XOR-swizzle per 4KB region: phys = byte ^ (((byte>>7)&3)<<4); dest
// linear, SOURCE pre-swizzled, reads use slot = kg ^ ((r>>1)&3).
__device__ __forceinline__ void gemm_mainloop(const _Float16* __restrict__ A,
                                              const _Float16* __restrict__ BT,
                                              int lda, int kbase, int m0, int c0,
                                              _Float16 (&ls)[2][12288],
                                              floatx4 (&acc)[4][2]){
  const int nsc  = kbase >> 5;       // fused chunks
  const int ldbt = 2*kbase;
  const int tid  = threadIdx.x;
  const int wave = tid >> 6, lane = tid & 63;
  const int wm = wave & 1, wn = wave >> 1;
  const int r = lane & 15, kg = lane >> 4;
  const int slot = kg ^ ((r >> 1) & 3);

  auto stage = [&](int c, int buf){
    const int ka = c << 5;
    char* lb = (char*)(&ls[buf][0]);
    #pragma unroll
    for (int p = 0; p < 2; ++p){                     // A hi, A lo: 8 KB each
      const int lbase = wave*1024 + p*4096;
      const int off = lbase + lane*16;
      const int row = off >> 6;
      const int bir = (off & 63) ^ (((off >> 7) & 3) << 4);  // pre-swizzled src
      const char* gah = (const char*)A + (((size_t)(m0 + row))*lda + ka)*2 + bir;
      stage16(gah, lb + lbase);                      // A_hi [0,8192)
      const char* gal = (const char*)A + (((size_t)(m0 + row))*lda + kbase + ka)*2 + bir;
      stage16(gal, lb + 8192 + lbase);               // A_lo [8192,16384)
    }
    {                                                // B hi, B lo: 4 KB each
      const int lbase = wave*1024;
      const int off = lbase + lane*16;
      const int row = off >> 6;
      const int bir = (off & 63) ^ (((off >> 7) & 3) << 4);
      const char* gbh = (const char*)BT + (((size_t)(c0 + row))*ldbt + ka)*2 + bir;
      stage16(gbh, lb + 16384 + lbase);              // B_hi [16384,20480)
      const char* gbl = (const char*)BT + (((size_t)(c0 + row))*ldbt + kbase + ka)*2 + bir;
      stage16(gbl, lb + 20480 + lbase);              // B_lo [20480,24576)
    }
  };

  stage(0, 0);
  for (int c = 0; c < nsc; ++c){
    __syncthreads();                      // drains vmcnt -> buf[c&1] ready
    if (c + 1 < nsc) stage(c + 1, (c + 1) & 1);
    const char* base = (const char*)&ls[c & 1][0];
    half8 ah[4], al[4], bh[2], bl[2];
    #pragma unroll
    for (int mt = 0; mt < 4; ++mt){
      const int ro = (wm*64 + mt*16 + r)*64 + slot*16;
      ah[mt] = *(const half8*)(base + ro);
      al[mt] = *(const half8*)(base + 8192 + ro);
    }
    #pragma unroll
    for (int nt = 0; nt < 2; ++nt){
      const int ro = (wn*32 + nt*16 + r)*64 + slot*16;
      bh[nt] = *(const half8*)(base + 16384 + ro);
      bl[nt] = *(const half8*)(base + 20480 + ro);
    }
    #pragma unroll
    for (int mt = 0; mt < 4; ++mt)
      #pragma unroll
      for (int nt = 0; nt < 2; ++nt)
        acc[mt][nt] = __builtin_amdgcn_mfma_f32_16x16x32_f16(ah[mt], bh[nt], acc[mt][nt], 0, 0, 0);
    #pragma unroll
    for (int mt = 0; mt < 4; ++mt)
      #pragma unroll
      for (int nt = 0; nt < 2; ++nt)
        acc[mt][nt] = __builtin_amdgcn_mfma_f32_16x16x32_f16(ah[mt], bl[nt], acc[mt][nt], 0, 0, 0);
    #pragma unroll
    for (int mt = 0; mt < 4; ++mt)
      #pragma unroll
      for (int nt = 0; nt < 2; ++nt)
        acc[mt][nt] = __builtin_amdgcn_mfma_f32_16x16x32_f16(al[mt], bh[nt], acc[mt][nt], 0, 0, 0);
  }
}

// MODE 1: silu + hi/lo split into OUT (=A2, lda 768, lo at +384).
// MODE 2: fused gating epilogue (G never materialized):
//   c0<384 : A1 <- (A1hi+A1lo)*g in place (patch RMW through LDS)
//   c0>=384: A4[(n*3+d)*512+mm] <- vec[n,mm,d]*g hi/lo
// MERGED phases: full 128-row patches in the 48 KB LDS; ALL 4 waves modify.
// Scratch XOR swizzle pc = cl ^ (kg<<4) matched by the movers' chunk XOR
// (rows 64..127 keep the (rl>>2)&3 == kg relation).
template<int MODE>
__global__ __launch_bounds__(256, 3) void gemm_split(const _Float16* __restrict__ A,
                                                     const _Float16* __restrict__ BT,
                                                     _Float16* __restrict__ OUT,
                                                     const float* __restrict__ S,
                                                     const float* __restrict__ V,
                                                     _Float16* __restrict__ A1g,
                                                     _Float16* __restrict__ A4,
                                                     int lda, int kbase, int nx, int ny){
  __shared__ alignas(16) _Float16 ls[2][12288];   // 48 KB
  int bx, by; remap_xcd(blockIdx.x, nx, ny, bx, by);
  const int c0 = bx << 6, m0 = by << 7;
  floatx4 acc[4][2];
  #pragma unroll
  for (int i = 0; i < 4; ++i)
    #pragma unroll
    for (int j = 0; j < 2; ++j) acc[i][j] = (floatx4){0.f, 0.f, 0.f, 0.f};

  gemm_mainloop(A, BT, lda, kbase, m0, c0, ls, acc);

  const int tid = threadIdx.x;
  const int wave = tid >> 6, lane = tid & 63;
  const int wm = wave & 1, wn = wave >> 1;
  const int r = lane & 15, kg = lane >> 4;
  char* scr = (char*)&ls[0][0];                   // epilogue scratch (<=32 KB)

  if (MODE == 1){
    __syncthreads();                              // k-loop reads done
    #pragma unroll
    for (int mt = 0; mt < 4; ++mt)
      #pragma unroll
      for (int nt = 0; nt < 2; ++nt)
        #pragma unroll
        for (int i = 0; i < 4; ++i){
          int rl = wm*64 + mt*16 + kg*4 + i;      // 0..127
          int cl = wn*32 + nt*16 + r;             // 0..63
          int pc = cl ^ (kg << 4);
          float g = acc[mt][nt][i];
          float hh = g / (1.0f + __expf(-g));     // silu
          *(unsigned int*)(scr + rl*256 + pc*4) = pack_split(hh);
        }
    __syncthreads();
    #pragma unroll 1
    for (int j = 0; j < 8; ++j){                  // 128 rows x 256 B = 32 KB
      int lin = j*256 + tid, rl = lin >> 4, seg = lin & 15;
      int cs = seg ^ (((rl >> 2) & 3) << 2);
      uint4 p = *(const uint4*)(scr + rl*256 + cs*16);
      uint2 hi, lo; unzip16(p, hi, lo);
      _Float16* rowp = OUT + (size_t)(m0 + rl)*768 + c0 + seg*4;
      *(uint2*)rowp         = hi;
      *(uint2*)(rowp + 384) = lo;
    }
  } else if (c0 < 384){
    // ---- sc-gate: RMW the A1 hi/lo 128x64 patch through LDS
    __syncthreads();
    #pragma unroll 1
    for (int j = 0; j < 4; ++j){                  // hi 16 KB + lo 16 KB
      int lin = j*256 + tid, rl = lin >> 3, seg = lin & 7;
      int cs = seg ^ (((rl >> 2) & 3) << 1);
      const _Float16* gp = A1g + (size_t)(m0 + rl)*768 + c0 + seg*8;
      *(float4*)(scr + rl*128 + cs*16)         = *(const float4*)gp;         // hi
      *(float4*)(scr + 16384 + rl*128 + cs*16) = *(const float4*)(gp + 384); // lo
    }
    __syncthreads();
    #pragma unroll
    for (int mt = 0; mt < 4; ++mt)
      #pragma unroll
      for (int nt = 0; nt < 2; ++nt)
        #pragma unroll
        for (int i = 0; i < 4; ++i){
          int rl = wm*64 + mt*16 + kg*4 + i;
          int cl = wn*32 + nt*16 + r;
          int pc = cl ^ (kg << 4);
          _Float16* phi = (_Float16*)scr + rl*64 + pc;
          _Float16* plo = (_Float16*)(scr + 16384) + rl*64 + pc;
          float sc = (float)*phi + (float)*plo;
          split_store(phi, plo, sc * acc[mt][nt][i]);
        }
    __syncthreads();
    #pragma unroll 1
    for (int j = 0; j < 4; ++j){
      int lin = j*256 + tid, rl = lin >> 3, seg = lin & 7;
      int cs = seg ^ (((rl >> 2) & 3) << 1);
      _Float16* gp = A1g + (size_t)(m0 + rl)*768 + c0 + seg*8;
      *(float4*)gp         = *(const float4*)(scr + rl*128 + cs*16);
      *(float4*)(gp + 384) = *(const float4*)(scr + 16384 + rl*128 + cs*16);
    }
  } else {
    // ---- vec-gate: c0 in {384,448,512,576}; mm panel = c0-384
    const int mm0 = c0 - 384;
    const int ch0 = mm0 & 127;
    if (mm0 >= 128){
      // fold sqrt2*S into acc once
      #pragma unroll
      for (int mt = 0; mt < 4; ++mt)
        #pragma unroll
        for (int nt = 0; nt < 2; ++nt)
          #pragma unroll
          for (int i = 0; i < 4; ++i){
            int row = m0 + wm*64 + mt*16 + kg*4 + i;
            int cl  = wn*32 + nt*16 + r;
            acc[mt][nt][i] *= 1.4142135623730951f * S[(size_t)row*128 + ch0 + cl];
          }
    }
    for (int d = 0; d < 3; ++d){
      __syncthreads();
      #pragma unroll 1
      for (int j = 0; j < 8; ++j){                // V patch: 128 rows x 256 B
        int lin = j*256 + tid, rl = lin >> 4, seg = lin & 15;
        int cs = seg ^ (((rl >> 2) & 3) << 2);
        *(float4*)(scr + rl*256 + cs*16) =
          *(const float4*)(V + ((size_t)(m0 + rl)*3 + d)*128 + ch0 + seg*4);
      }
      __syncthreads();
      #pragma unroll
      for (int mt = 0; mt < 4; ++mt)
        #pragma unroll
        for (int nt = 0; nt < 2; ++nt)
          #pragma unroll
          for (int i = 0; i < 4; ++i){
            int rl = wm*64 + mt*16 + kg*4 + i;
            int cl = wn*32 + nt*16 + r;
            int pc = cl ^ (kg << 4);
            float* pw = (float*)(scr + rl*256) + pc;
            *(unsigned int*)pw = pack_split(*pw * acc[mt][nt][i]);
          }
      __syncthreads();
      #pragma unroll 1
      for (int j = 0; j < 8; ++j){
        int lin = j*256 + tid, rl = lin >> 4, seg = lin & 15;
        int cs = seg ^ (((rl >> 2) & 3) << 2);
        uint4 p = *(const uint4*)(scr + rl*256 + cs*16);
        uint2 hi, lo; unzip16(p, hi, lo);
        _Float16* rowp = A4 + ((size_t)(m0 + rl)*3 + d)*512 + mm0 + seg*4;
        *(uint2*)rowp         = hi;
        *(uint2*)(rowp + 256) = lo;
      }
    }
  }
}

// GEMM0 (A1 x W0 -> OS, 2*ny0 blocks) and GEMMV (A4 x WV -> OV, 2*ny1 blocks)
// in one dispatch; each part XCD-remapped; plain f32 coalesced store.
__global__ __launch_bounds__(256, 3) void gemm_pair(const _Float16* __restrict__ Aa,
                                                    const _Float16* __restrict__ Ba,
                                                    float* __restrict__ Ca, int ny0,
                                                    const _Float16* __restrict__ Ab,
                                                    const _Float16* __restrict__ Bb,
                                                    float* __restrict__ Cb, int ny1){
  __shared__ alignas(16) _Float16 ls[2][12288];
  const _Float16 *A, *BT; float* C; int lda, kbase, bx, by;
  const int id = blockIdx.x;
  if (id < 2*ny0){
    remap_xcd(id, 2, ny0, bx, by);
    A = Aa; BT = Ba; C = Ca; lda = 768; kbase = 384;
  } else {
    remap_xcd(id - 2*ny0, 2, ny1, bx, by);
    A = Ab; BT = Bb; C = Cb; lda = 512; kbase = 256;
  }
  const int c0 = bx << 6, m0 = by << 7;
  floatx4 acc[4][2];
  #pragma unroll
  for (int i = 0; i < 4; ++i)
    #pragma unroll
    for (int j = 0; j < 2; ++j) acc[i][j] = (floatx4){0.f, 0.f, 0.f, 0.f};

  gemm_mainloop(A, BT, lda, kbase, m0, c0, ls, acc);

  const int wave = threadIdx.x >> 6, lane = threadIdx.x & 63;
  const int wm = wave & 1, wn = wave >> 1;
  const int r = lane & 15, kg = lane >> 4;
  #pragma unroll
  for (int mt = 0; mt < 4; ++mt)
    #pragma unroll
    for (int nt = 0; nt < 2; ++nt)
      #pragma unroll
      for (int i = 0; i < 4; ++i){
        const int row = m0 + wm*64 + mt*16 + kg*4 + i;
        const int col = c0 + wn*32 + nt*16 + r;
        C[(size_t)row*128 + col] = acc[mt][nt][i];
      }
}

// ---------------------------- host launcher --------------------------------

extern "C" void kernel_launch(void* const* d_in, const int* in_sizes, int n_in,
                              void* d_out, int out_size, void* d_ws, size_t ws_size,
                              hipStream_t stream){
  const float* x  = (const float*)d_in[0];
  const float* w1 = (const float*)d_in[1];
  const float* w2 = (const float*)d_in[2];
  const float* w0 = (const float*)d_in[3];
  const float* wv = (const float*)d_in[4];
  const float* g0 = (const float*)d_in[5];
  const float* g1 = (const float*)d_in[6];
  float* out = (float*)d_out;
  const int N = in_sizes[0] / 512;                 // 16384

  // split-weight arena: per layer 950,272 halves ([col][2K] hi|lo)
  const size_t HL = 950272;
  _Float16* W = (_Float16*)d_ws;
  const size_t wbytes = 2*HL*2;                    // 3,801,088 B

  // pick N-chunking that fits ws (activations cost 10240 B/row)
  int cnum = 128;
  for (int cc = 1; cc <= 128; cc <<= 1){
    size_t need = wbytes + (size_t)(N/cc)*10240;
    if (need <= ws_size){ cnum = cc; break; }
  }
  const int R = N / cnum;                          // multiple of 128
  const int ny = R / 128;

  char* p = (char*)d_ws + wbytes;
  float*    Sst = (float*)p;     p += (size_t)R*512;
  float*    Vst = (float*)p;     p += (size_t)R*1536;
  _Float16* A1  = (_Float16*)p;  p += (size_t)R*1536;   // sc' then gated sc'
  _Float16* A2  = (_Float16*)p;  p += (size_t)R*1536;   // h'
  _Float16* A4  = (_Float16*)p;  p += (size_t)R*3072;   // gated vec' (3R x 512)
  float*    OS  = (float*)p;     p += (size_t)R*512;
  float*    OV  = (float*)p;     p += (size_t)R*1536;

  // weight prep (runs every call; ws is re-poisoned before each timed launch)
  prep_all<<<cdiv_h(2*475136,256),256,0,stream>>>(w1, w2, w0, wv, W);

  for (int chk = 0; chk < cnum; ++chk){
    const int row0 = chk*R;
    e0_fused<<<R/4,256,0,stream>>>(x, Sst, Vst, A1, row0);
    for (int l = 0; l < 2; ++l){
      _Float16* W1p = W + (size_t)l*HL;
      _Float16* W2p = W1p + 294912;
      _Float16* W0p = W1p + 786432;
      _Float16* WVp = W1p + 884736;
      gemm_split<1><<<6*ny,256,0,stream>>>(A1, W1p, A2,
          nullptr, nullptr, nullptr, nullptr, 768, 384, 6, ny);
      gemm_split<2><<<10*ny,256,0,stream>>>(A2, W2p, nullptr,
          Sst, Vst, A1, A4, 768, 384, 10, ny);
      gemm_pair<<<8*ny,256,0,stream>>>(A1, W0p, OS, ny, A4, WVp, OV, 3*ny);
      e3_fin<<<R/4,256,0,stream>>>(Sst, Vst, OS, OV, g0, g1, out, A1, row0, (l == 0) ? 1 : 0);
    }
  }
}